// Round 5
// baseline (71.815 us; speedup 1.0000x reference)
//
#include <hip/hip_runtime.h>
#include <hip/hip_fp16.h>

typedef float f32x4 __attribute__((ext_vector_type(4)));

#define N_SAMPLES 64
#define M_ELEMS   307200              // 480*640 per-sample elements
#define M4        76800               // float4 per sample
#define BLOCK     256
#define BPS       20                  // blocks per sample
#define TPS       (BPS * BLOCK)       // 5120 threads per sample
#define ITERS     (M4 / TPS)          // 15 float4 per thread, exact
#define NBLOCKS   (BPS * N_SAMPLES)   // 1280 = 5 blocks/CU on 256 CUs
#define NUM_CU    256
#define SCALE     (1.0f / ((float)M_ELEMS * (float)N_SAMPLES))

__device__ __forceinline__ float wave_reduce_max(float v) {
    #pragma unroll
    for (int off = 32; off > 0; off >>= 1)
        v = fmaxf(v, __shfl_down(v, off, 64));
    return v;
}
__device__ __forceinline__ float wave_reduce_sum(float v) {
    #pragma unroll
    for (int off = 32; off > 0; off >>= 1)
        v += __shfl_down(v, off, 64);
    return v;
}

// Fused single-read kernel, NT loads: stream inputs once from HBM without
// cache retention (kills the scattered L3-half-miss pattern between graph
// replays), hold |d| as packed fp16 in 30 statically-indexed VGPRs,
// per-sample device-scope sync, BerHu from registers. No large writes.
__global__ __launch_bounds__(BLOCK, 5) void berhu_fused(
        const float* __restrict__ pred,
        const float* __restrict__ targ,
        unsigned int* __restrict__ maxbits,
        unsigned int* __restrict__ done,
        float* __restrict__ out) {
    const int n = blockIdx.y;
    const f32x4* p = (const f32x4*)(pred + (size_t)n * M_ELEMS);
    const f32x4* t = (const f32x4*)(targ + (size_t)n * M_ELEMS);
    const int i0 = blockIdx.x * BLOCK + threadIdx.x;

    unsigned int adp[2 * ITERS];     // 30 VGPRs of packed half2 |d|
    float m = 0.0f;
    #pragma unroll
    for (int k = 0; k < ITERS; ++k) {
        f32x4 a = __builtin_nontemporal_load(p + i0 + k * TPS);
        f32x4 b = __builtin_nontemporal_load(t + i0 + k * TPS);
        float ad0 = fabsf(a[0] - b[0]);
        float ad1 = fabsf(a[1] - b[1]);
        float ad2 = fabsf(a[2] - b[2]);
        float ad3 = fabsf(a[3] - b[3]);
        m = fmaxf(m, fmaxf(fmaxf(ad0, ad1), fmaxf(ad2, ad3)));
        adp[2 * k]     = __builtin_bit_cast(unsigned int, __floats2half2_rn(ad0, ad1));
        adp[2 * k + 1] = __builtin_bit_cast(unsigned int, __floats2half2_rn(ad2, ad3));
    }

    // block-reduce max
    m = wave_reduce_max(m);
    __shared__ float sred[BLOCK / 64];
    __shared__ float sc;
    const int wid  = threadIdx.x >> 6;
    const int lane = threadIdx.x & 63;
    if (lane == 0) sred[wid] = m;
    __syncthreads();
    if (threadIdx.x == 0) {
        float bm = sred[0];
        #pragma unroll
        for (int w = 1; w < BLOCK / 64; ++w) bm = fmaxf(bm, sred[w]);
        atomicMax(&maxbits[n], __float_as_uint(bm));   // |d|>=0: bit cmp == float cmp
        __threadfence();                               // maxbits visible before done++
        atomicAdd(&done[n], 1u);
        // Blocks of a sample dispatch contiguously; spin resolves even under
        // partial residency as long as >=BPS blocks fit (trivially true).
        while (atomicMax(&done[n], 0u) < (unsigned)BPS)
            __builtin_amdgcn_s_sleep(8);
        sc = __uint_as_float(atomicMax(&maxbits[n], 0u)) * 0.2f;  // fresh read via RMW
    }
    __syncthreads();

    const float c = sc;
    const float c2 = c * c;
    const float inv2c = (c > 0.0f) ? (0.5f / c) : 0.0f;

    float s = 0.0f;
    #pragma unroll
    for (int k = 0; k < 2 * ITERS; ++k) {
        __half2 h = __builtin_bit_cast(__half2, adp[k]);
        float fx = __low2float(h);
        float fy = __high2float(h);
        s += (fx <= c) ? fx : (fx * fx + c2) * inv2c;
        s += (fy <= c) ? fy : (fy * fy + c2) * inv2c;
    }

    s = wave_reduce_sum(s);
    __syncthreads();                 // sred reuse
    if (lane == 0) sred[wid] = s;
    __syncthreads();
    if (threadIdx.x == 0) {
        float bs = sred[0];
        #pragma unroll
        for (int w = 1; w < BLOCK / 64; ++w) bs += sred[w];
        atomicAdd(out, bs * SCALE);
    }
}

// ---- fallback: proven two-pass (R1 structure), NT loads ----
__global__ __launch_bounds__(BLOCK) void fb_max(
        const float* __restrict__ pred, const float* __restrict__ targ,
        unsigned int* __restrict__ maxbits) {
    const int n = blockIdx.y;
    const f32x4* p = (const f32x4*)(pred + (size_t)n * M_ELEMS);
    const f32x4* t = (const f32x4*)(targ + (size_t)n * M_ELEMS);
    float m = 0.0f;
    for (int i = blockIdx.x * BLOCK + threadIdx.x; i < M4; i += TPS) {
        f32x4 a = __builtin_nontemporal_load(p + i);
        f32x4 b = __builtin_nontemporal_load(t + i);
        m = fmaxf(m, fmaxf(fmaxf(fabsf(a[0]-b[0]), fabsf(a[1]-b[1])),
                           fmaxf(fabsf(a[2]-b[2]), fabsf(a[3]-b[3]))));
    }
    m = wave_reduce_max(m);
    __shared__ float smax[BLOCK / 64];
    if ((threadIdx.x & 63) == 0) smax[threadIdx.x >> 6] = m;
    __syncthreads();
    if (threadIdx.x == 0) {
        float bm = smax[0];
        for (int w = 1; w < BLOCK / 64; ++w) bm = fmaxf(bm, smax[w]);
        atomicMax(&maxbits[n], __float_as_uint(bm));
    }
}
__global__ __launch_bounds__(BLOCK) void fb_sum(
        const float* __restrict__ pred, const float* __restrict__ targ,
        const unsigned int* __restrict__ maxbits, float* __restrict__ out) {
    const int n = blockIdx.y;
    const float c = __uint_as_float(maxbits[n]) * 0.2f;
    const float c2 = c * c;
    const float inv2c = (c > 0.0f) ? (0.5f / c) : 0.0f;
    const f32x4* p = (const f32x4*)(pred + (size_t)n * M_ELEMS);
    const f32x4* t = (const f32x4*)(targ + (size_t)n * M_ELEMS);
    float s = 0.0f;
    for (int i = blockIdx.x * BLOCK + threadIdx.x; i < M4; i += TPS) {
        f32x4 a = __builtin_nontemporal_load(p + i);
        f32x4 b = __builtin_nontemporal_load(t + i);
        #pragma unroll
        for (int q = 0; q < 4; ++q) {
            float d = a[q] - b[q], ad = fabsf(d);
            s += (ad <= c) ? ad : (d * d + c2) * inv2c;
        }
    }
    s = wave_reduce_sum(s);
    __shared__ float ssum[BLOCK / 64];
    if ((threadIdx.x & 63) == 0) ssum[threadIdx.x >> 6] = s;
    __syncthreads();
    if (threadIdx.x == 0) {
        float bs = ssum[0];
        for (int w = 1; w < BLOCK / 64; ++w) bs += ssum[w];
        atomicAdd(out, bs * SCALE);
    }
}

extern "C" void kernel_launch(void* const* d_in, const int* in_sizes, int n_in,
                              void* d_out, int out_size, void* d_ws, size_t ws_size,
                              hipStream_t stream) {
    const float* pred = (const float*)d_in[0];
    const float* targ = (const float*)d_in[1];
    float* out = (float*)d_out;

    unsigned int* maxbits = (unsigned int*)d_ws;              // [64]
    unsigned int* done    = (unsigned int*)d_ws + N_SAMPLES;  // [64]

    // ws/out poisoned 0xAA, not re-poisoned between replays — zero every call.
    hipMemsetAsync(d_ws, 0, 2 * N_SAMPLES * sizeof(unsigned int), stream);
    hipMemsetAsync(d_out, 0, sizeof(float), stream);

    // Residency gate for the spin-sync (deterministic host query, capture-safe).
    int nb = 0;
    hipError_t qe = hipOccupancyMaxActiveBlocksPerMultiprocessor(
        &nb, (const void*)berhu_fused, BLOCK, 0);
    const bool coop_ok = (qe == hipSuccess) && (nb * NUM_CU >= NBLOCKS);

    dim3 grid(BPS, N_SAMPLES);
    if (coop_ok) {
        berhu_fused<<<grid, BLOCK, 0, stream>>>(pred, targ, maxbits, done, out);
    } else {
        fb_max<<<grid, BLOCK, 0, stream>>>(pred, targ, maxbits);
        fb_sum<<<grid, BLOCK, 0, stream>>>(pred, targ, maxbits, out);
    }
}

// Round 6
// 69.816 us; speedup vs baseline: 1.0286x; 1.0286x over previous
//
#include <hip/hip_runtime.h>

typedef float f32x4 __attribute__((ext_vector_type(4)));

#define N_SAMPLES 64
#define M_ELEMS   307200            // 480*640 per-sample elements
#define M4        76800             // float4 per sample
#define BLOCK     256
#define BPS       25                // blocks per sample
#define TPS       (BPS * BLOCK)     // 6400 threads per sample
#define ITERS     (M4 / TPS)        // exactly 12 float4 per thread
#define SCALE     (1.0f / ((float)M_ELEMS * (float)N_SAMPLES))

__device__ __forceinline__ float wave_reduce_max(float v) {
    #pragma unroll
    for (int off = 32; off > 0; off >>= 1)
        v = fmaxf(v, __shfl_down(v, off, 64));
    return v;
}
__device__ __forceinline__ float wave_reduce_sum(float v) {
    #pragma unroll
    for (int off = 32; off > 0; off >>= 1)
        v += __shfl_down(v, off, 64);
    return v;
}

// Pass 1: per-sample max of |pred-targ|, with FORCED 24-deep load pipeline.
// The asm ties + memory clobber pin all 24 global loads before any consume:
// loads can't sink below the clobber, consumes depend on asm outputs so they
// can't hoist above it. This is what R2 tried and the compiler defeated
// (VGPR_Count=36 proved only ~4 loads in flight).
__global__ __launch_bounds__(BLOCK, 4) void berhu_max_kernel(
        const float* __restrict__ pred,
        const float* __restrict__ targ,
        unsigned int* __restrict__ maxbits) {
    const int n = blockIdx.y;
    const f32x4* p = (const f32x4*)(pred + (size_t)n * M_ELEMS);
    const f32x4* t = (const f32x4*)(targ + (size_t)n * M_ELEMS);
    const int i0 = blockIdx.x * BLOCK + threadIdx.x;

    f32x4 a[ITERS], b[ITERS];
    #pragma unroll
    for (int k = 0; k < ITERS; ++k) a[k] = p[i0 + k * TPS];
    #pragma unroll
    for (int k = 0; k < ITERS; ++k) b[k] = t[i0 + k * TPS];

    // Pin: all loads issued before this point; all consumes after.
    asm volatile("" : "+v"(a[0]), "+v"(a[1]), "+v"(a[2]),  "+v"(a[3]),
                      "+v"(a[4]), "+v"(a[5]), "+v"(a[6]),  "+v"(a[7]),
                      "+v"(a[8]), "+v"(a[9]), "+v"(a[10]), "+v"(a[11])
                    :: "memory");
    asm volatile("" : "+v"(b[0]), "+v"(b[1]), "+v"(b[2]),  "+v"(b[3]),
                      "+v"(b[4]), "+v"(b[5]), "+v"(b[6]),  "+v"(b[7]),
                      "+v"(b[8]), "+v"(b[9]), "+v"(b[10]), "+v"(b[11])
                    :: "memory");
    __builtin_amdgcn_sched_barrier(0);

    float m = 0.0f;
    #pragma unroll
    for (int k = 0; k < ITERS; ++k) {
        m = fmaxf(m, fabsf(a[k][0] - b[k][0]));
        m = fmaxf(m, fabsf(a[k][1] - b[k][1]));
        m = fmaxf(m, fabsf(a[k][2] - b[k][2]));
        m = fmaxf(m, fabsf(a[k][3] - b[k][3]));
    }

    m = wave_reduce_max(m);
    __shared__ float smax[BLOCK / 64];
    const int wid  = threadIdx.x >> 6;
    const int lane = threadIdx.x & 63;
    if (lane == 0) smax[wid] = m;
    __syncthreads();
    if (threadIdx.x == 0) {
        float bm = smax[0];
        #pragma unroll
        for (int w = 1; w < BLOCK / 64; ++w) bm = fmaxf(bm, smax[w]);
        atomicMax(&maxbits[n], __float_as_uint(bm));   // |d|>=0: bit cmp == float cmp
    }
}

// Pass 2: BerHu sum; inputs are L3-hot from pass 1 (R1 measured ~15.7 TB/s
// here), so the simple loop suffices. Scaled atomic straight into out[0].
__global__ __launch_bounds__(BLOCK) void berhu_sum_kernel(
        const float* __restrict__ pred,
        const float* __restrict__ targ,
        const unsigned int* __restrict__ maxbits,
        float* __restrict__ out) {
    const int n = blockIdx.y;
    const float c = __uint_as_float(maxbits[n]) * 0.2f;   // max/5
    const float c2 = c * c;
    const float inv2c = (c > 0.0f) ? (0.5f / c) : 0.0f;

    const f32x4* p = (const f32x4*)(pred + (size_t)n * M_ELEMS);
    const f32x4* t = (const f32x4*)(targ + (size_t)n * M_ELEMS);

    float s = 0.0f;
    int i = blockIdx.x * BLOCK + threadIdx.x;
    #pragma unroll
    for (int k = 0; k < ITERS; ++k, i += TPS) {
        f32x4 a = p[i];
        f32x4 b = t[i];
        #pragma unroll
        for (int q = 0; q < 4; ++q) {
            float d = a[q] - b[q], ad = fabsf(d);
            s += (ad <= c) ? ad : (d * d + c2) * inv2c;
        }
    }

    s = wave_reduce_sum(s);
    __shared__ float ssum[BLOCK / 64];
    const int wid  = threadIdx.x >> 6;
    const int lane = threadIdx.x & 63;
    if (lane == 0) ssum[wid] = s;
    __syncthreads();
    if (threadIdx.x == 0) {
        float bs = ssum[0];
        #pragma unroll
        for (int w = 1; w < BLOCK / 64; ++w) bs += ssum[w];
        atomicAdd(out, bs * SCALE);
    }
}

extern "C" void kernel_launch(void* const* d_in, const int* in_sizes, int n_in,
                              void* d_out, int out_size, void* d_ws, size_t ws_size,
                              hipStream_t stream) {
    const float* pred = (const float*)d_in[0];
    const float* targ = (const float*)d_in[1];
    float* out = (float*)d_out;

    unsigned int* maxbits = (unsigned int*)d_ws;

    // ws/out poisoned 0xAA, not re-poisoned between replays — zero every call.
    hipMemsetAsync(d_ws, 0, N_SAMPLES * sizeof(unsigned int), stream);
    hipMemsetAsync(d_out, 0, sizeof(float), stream);

    dim3 grid(BPS, N_SAMPLES);
    berhu_max_kernel<<<grid, BLOCK, 0, stream>>>(pred, targ, maxbits);
    berhu_sum_kernel<<<grid, BLOCK, 0, stream>>>(pred, targ, maxbits, out);
}